// Round 1
// baseline (442.838 us; speedup 1.0000x reference)
//
#include <hip/hip_runtime.h>
#include <hip/hip_bf16.h>

#define DEV static __device__ __forceinline__

typedef __attribute__((ext_vector_type(8))) short short8;
typedef __attribute__((ext_vector_type(4))) float f32x4;

// ---------- helpers ----------
DEV unsigned short f2b(float f){
  unsigned int u = __float_as_uint(f);
  return (unsigned short)((u + 0x7FFFu + ((u >> 16) & 1u)) >> 16);  // RNE
}
DEV float b2f(unsigned short h){ return __uint_as_float(((unsigned int)h) << 16); }
DEV float load_in(const void* p, size_t i, int isbf){
  return isbf ? b2f(((const unsigned short*)p)[i]) : ((const float*)p)[i];
}

// ---------- dtype detection ----------
// If inputs are stored fp32, the EVEN ushort of each word is float mantissa
// garbage -> rarely a sane bf16. If stored bf16, every ushort is a sane value.
__global__ void detect_kernel(const void* src, int* flag){
  int tid = threadIdx.x;
  float v = b2f(((const unsigned short*)src)[2 * tid]);
  float av = fabsf(v);
  bool sane = ((av < 64.0f) && (av > 9.5e-7f)) || (v == 0.0f);
  unsigned long long m = __ballot(sane);
  __shared__ int cnt[4];
  if ((tid & 63) == 0) cnt[tid >> 6] = __popcll(m);
  __syncthreads();
  if (tid == 0) flag[0] = (cnt[0] + cnt[1] + cnt[2] + cnt[3] > 128) ? 1 : 0;
}

// ---------- weight ingest: fp32/bf16 [K][N] -> bf16 W^T [N][K] ----------
struct WDesc { const void* src; long src_off; unsigned short* dst; int K; int N; int tstart; };
struct WParams { WDesc d[12]; const int* flag; };

__global__ __launch_bounds__(256) void ingest_weights(WParams P){
  __shared__ float tile[32][33];
  int b = blockIdx.x;
  int t = 0;
  #pragma unroll
  for (int i = 1; i < 12; ++i) if (b >= P.d[i].tstart) t = i;
  WDesc d = P.d[t];
  int isbf = *P.flag;
  int r = b - d.tstart;
  int tiles_x = d.N >> 5;
  int tx = r % tiles_x, ty = r / tiles_x;
  int lx = threadIdx.x & 31, ly = threadIdx.x >> 5;   // 32 x 8
  #pragma unroll
  for (int i = 0; i < 4; ++i){
    int row = ty*32 + ly + i*8;
    int col = tx*32 + lx;
    tile[ly + i*8][lx] = load_in(d.src, (size_t)d.src_off + (size_t)row*d.N + col, isbf);
  }
  __syncthreads();
  #pragma unroll
  for (int i = 0; i < 4; ++i){
    int orow = tx*32 + ly + i*8;   // n
    int ocol = ty*32 + lx;         // k
    d.dst[(size_t)orow*d.K + ocol] = f2b(tile[lx][ly + i*8]);
  }
}

// ---------- small params ingest -> contiguous fp32 ----------
struct SDesc { const void* src; int start; };
struct SParams { SDesc d[12]; float* dst; const int* flag; int total; };

__global__ void ingest_smalls(SParams P){
  int i = blockIdx.x*256 + threadIdx.x;
  if (i >= P.total) return;
  int t = 0;
  #pragma unroll
  for (int j = 1; j < 12; ++j) if (i >= P.d[j].start) t = j;
  P.dst[i] = load_in(P.d[t].src, (size_t)(i - P.d[t].start), *P.flag);
}

__global__ void ingest_src(const void* src, const int* flag, float* xf,
                           unsigned short* xb, int n){
  int i = blockIdx.x*blockDim.x + threadIdx.x;
  if (i >= n) return;
  float v = load_in(src, (size_t)i, *flag);
  xf[i] = v; xb[i] = f2b(v);
}

// ---------- GEMM: C[M][N] = A[M][K] @ Bt[N][K]^T + bias (A,Bt bf16) ----------
// 128x128 tile, BK=32, 256 thr = 4 waves (2x2), each wave 4x4 of 16x16x32 MFMA.
// LDS rows padded to 40 elems (80B: 16B-aligned, 2-way bank aliasing = free).
struct GemmArgs {
  const unsigned short* A;
  const unsigned short* Bt[3];
  const float* bias[3];
  float* Cf[3];
  unsigned short* Cb[3];
  int M, N, K, relu;
};

__global__ __launch_bounds__(256) void gemm_bt(GemmArgs g){
  __shared__ unsigned short sA[128*40];
  __shared__ unsigned short sB[128*40];
  int tid = threadIdx.x;
  int z = blockIdx.z;
  const unsigned short* A  = g.A;
  const unsigned short* Bt = g.Bt[z];
  int K = g.K, N = g.N;
  size_t bm = (size_t)blockIdx.y * 128, bn = (size_t)blockIdx.x * 128;
  int lane = tid & 63, wv = tid >> 6, quad = lane >> 4, l16 = lane & 15;
  int wm = (wv >> 1) * 64, wn = (wv & 1) * 64;
  int r0 = tid >> 2, c0 = (tid & 3) * 8;
  f32x4 acc[4][4];
  #pragma unroll
  for (int i=0;i<4;++i)
    #pragma unroll
    for (int j=0;j<4;++j) acc[i][j] = (f32x4){0.f,0.f,0.f,0.f};
  const unsigned short* Ap = A  + (bm + r0)*K + c0;
  const unsigned short* Bp = Bt + (bn + r0)*K + c0;
  for (int ko = 0; ko < K; ko += 32){
    float4 a0 = *(const float4*)(Ap + ko);
    float4 a1 = *(const float4*)(Ap + (size_t)64*K + ko);
    float4 b0 = *(const float4*)(Bp + ko);
    float4 b1 = *(const float4*)(Bp + (size_t)64*K + ko);
    __syncthreads();
    *(float4*)&sA[r0*40 + c0]      = a0;
    *(float4*)&sA[(r0+64)*40 + c0] = a1;
    *(float4*)&sB[r0*40 + c0]      = b0;
    *(float4*)&sB[(r0+64)*40 + c0] = b1;
    __syncthreads();
    short8 af[4], bfv[4];
    #pragma unroll
    for (int i=0;i<4;++i) af[i]  = *(const short8*)&sA[(wm + i*16 + l16)*40 + quad*8];
    #pragma unroll
    for (int j=0;j<4;++j) bfv[j] = *(const short8*)&sB[(wn + j*16 + l16)*40 + quad*8];
    #pragma unroll
    for (int i=0;i<4;++i)
      #pragma unroll
      for (int j=0;j<4;++j)
        acc[i][j] = __builtin_amdgcn_mfma_f32_16x16x32_bf16(af[i], bfv[j], acc[i][j], 0,0,0);
  }
  const float* bias = g.bias[z];
  float* Cf = g.Cf[z];
  unsigned short* Cb = g.Cb[z];
  #pragma unroll
  for (int j=0;j<4;++j){
    int col = (int)bn + wn + j*16 + l16;
    float bv = bias[col];
    #pragma unroll
    for (int i=0;i<4;++i){
      #pragma unroll
      for (int r=0;r<4;++r){
        int row = (int)bm + wm + i*16 + quad*4 + r;
        float v = acc[i][j][r] + bv;
        if (g.relu) v = fmaxf(v, 0.f);
        size_t idx = (size_t)row*N + col;
        if (Cf) Cf[idx] = v;
        if (Cb) Cb[idx] = f2b(v);
      }
    }
  }
}

// ---------- chunked causal linear attention ----------
// One block per (b,h). Chunks of 64. KV^T state [n][k] fp32 in LDS.
// Per chunk: S = tril(Q K^T); att = Q@KV^T_old + S@V; KV^T += V^T K.
#define ATT_S 1024
#define ATT_D 512

__global__ __launch_bounds__(256) void attn_kernel(
    const unsigned short* q, const unsigned short* k, const unsigned short* v,
    unsigned short* att)
{
  __shared__ unsigned short sQ [64*72];
  __shared__ unsigned short sK [64*72];   // K chunk, later reused to hold S
  __shared__ unsigned short sVt[64*72];   // V^T [n][t]
  __shared__ unsigned short sKt[64*72];   // K^T [k][t]
  __shared__ float sKV[64*68];            // state KV^T [n][k] fp32

  int tid = threadIdx.x;
  int bh = blockIdx.x;
  int b = bh >> 3, h = bh & 7;
  const size_t base = ((size_t)b * ATT_S) * ATT_D + h * 64;

  int lane = tid & 63, wv = tid >> 6, quad = lane >> 4, l16 = lane & 15;

  for (int i = tid; i < 64*68; i += 256) sKV[i] = 0.f;
  __syncthreads();

  for (int c = 0; c < 16; ++c){
    int s0 = c * 64;
    // ---- stage (loads first, then barrier, then LDS stores) ----
    int r  = tid >> 2;            // 0..63
    int c8 = (tid & 3) * 8;       // 0,8,16,24 (+32 for second half)
    const unsigned short* qp = q + base + (size_t)(s0 + r)*ATT_D;
    const unsigned short* kp = k + base + (size_t)(s0 + r)*ATT_D;
    float4 q0 = *(const float4*)(qp + c8);
    float4 q1 = *(const float4*)(qp + c8 + 32);
    float4 k0 = *(const float4*)(kp + c8);
    float4 k1 = *(const float4*)(kp + c8 + 32);
    int t  = lane;                // 0..63
    int vc = (tid >> 6) * 8;      // 0,8,16,24 (+32)
    const unsigned short* vp  = v + base + (size_t)(s0 + t)*ATT_D;
    const unsigned short* kp2 = k + base + (size_t)(s0 + t)*ATT_D;
    float4 v0 = *(const float4*)(vp + vc);
    float4 v1 = *(const float4*)(vp + vc + 32);
    float4 kk0 = *(const float4*)(kp2 + vc);
    float4 kk1 = *(const float4*)(kp2 + vc + 32);
    __syncthreads();   // (A) prev-chunk LDS reads done
    *(float4*)&sQ[r*72 + c8]      = q0;
    *(float4*)&sQ[r*72 + c8 + 32] = q1;
    *(float4*)&sK[r*72 + c8]      = k0;
    *(float4*)&sK[r*72 + c8 + 32] = k1;
    {
      const unsigned short* pv0 = (const unsigned short*)&v0;
      const unsigned short* pv1 = (const unsigned short*)&v1;
      const unsigned short* pk0 = (const unsigned short*)&kk0;
      const unsigned short* pk1 = (const unsigned short*)&kk1;
      #pragma unroll
      for (int e = 0; e < 8; ++e){
        sVt[(vc+e)*72 + t]    = pv0[e];
        sVt[(vc+32+e)*72 + t] = pv1[e];
        sKt[(vc+e)*72 + t]    = pk0[e];
        sKt[(vc+32+e)*72 + t] = pk1[e];
      }
    }
    __syncthreads();   // (B) tiles visible

    // ---- matmul1: S rows [16w,16w+16) = Q K^T ----
    f32x4 accS[4];
    #pragma unroll
    for (int j=0;j<4;++j) accS[j] = (f32x4){0.f,0.f,0.f,0.f};
    #pragma unroll
    for (int kk = 0; kk < 2; ++kk){
      short8 a = *(const short8*)&sQ[(wv*16 + l16)*72 + kk*32 + quad*8];
      #pragma unroll
      for (int j=0;j<4;++j){
        short8 bb = *(const short8*)&sK[(j*16 + l16)*72 + kk*32 + quad*8];
        accS[j] = __builtin_amdgcn_mfma_f32_16x16x32_bf16(a, bb, accS[j], 0,0,0);
      }
    }
    __syncthreads();   // (C) all waves done reading sK

    // ---- masked S -> sK (as bf16) ----
    #pragma unroll
    for (int j=0;j<4;++j)
      #pragma unroll
      for (int rr=0;rr<4;++rr){
        int i  = wv*16 + quad*4 + rr;
        int cj = j*16 + l16;
        sK[i*72 + cj] = f2b((i >= cj) ? accS[j][rr] : 0.f);
      }

    // ---- matmul4: att = Q @ KV^T_old (state bf16-converted on the fly) ----
    f32x4 accO[4];
    #pragma unroll
    for (int j=0;j<4;++j) accO[j] = (f32x4){0.f,0.f,0.f,0.f};
    #pragma unroll
    for (int kk=0; kk<2; ++kk){
      short8 a = *(const short8*)&sQ[(wv*16 + l16)*72 + kk*32 + quad*8];
      #pragma unroll
      for (int j=0;j<4;++j){
        const float* pf = &sKV[(j*16 + l16)*68 + kk*32 + quad*8];
        short8 bb;
        #pragma unroll
        for (int e=0;e<8;++e) ((unsigned short*)&bb)[e] = f2b(pf[e]);
        accO[j] = __builtin_amdgcn_mfma_f32_16x16x32_bf16(a, bb, accO[j], 0,0,0);
      }
    }
    __syncthreads();   // (D) S visible; state reads done before update

    // ---- matmul3: att += S @ V (B-operand = V^T) ----
    #pragma unroll
    for (int kk=0;kk<2;++kk){
      short8 a = *(const short8*)&sK[(wv*16 + l16)*72 + kk*32 + quad*8];
      #pragma unroll
      for (int j=0;j<4;++j){
        short8 bb = *(const short8*)&sVt[(j*16 + l16)*72 + kk*32 + quad*8];
        accO[j] = __builtin_amdgcn_mfma_f32_16x16x32_bf16(a, bb, accO[j], 0,0,0);
      }
    }
    // write att (bf16)
    #pragma unroll
    for (int j=0;j<4;++j)
      #pragma unroll
      for (int rr=0;rr<4;++rr){
        int i  = wv*16 + quad*4 + rr;
        int cj = j*16 + l16;
        att[base + (size_t)(s0 + i)*ATT_D + cj] = f2b(accO[j][rr]);
      }

    // ---- matmul5: KV^T rows [16w,16w+16) += V^T K ----
    f32x4 accU[4];
    #pragma unroll
    for (int j=0;j<4;++j) accU[j] = (f32x4){0.f,0.f,0.f,0.f};
    #pragma unroll
    for (int kk=0;kk<2;++kk){
      short8 a = *(const short8*)&sVt[(wv*16 + l16)*72 + kk*32 + quad*8];
      #pragma unroll
      for (int j=0;j<4;++j){
        short8 bb = *(const short8*)&sKt[(j*16 + l16)*72 + kk*32 + quad*8];
        accU[j] = __builtin_amdgcn_mfma_f32_16x16x32_bf16(a, bb, accU[j], 0,0,0);
      }
    }
    #pragma unroll
    for (int j=0;j<4;++j)
      #pragma unroll
      for (int rr=0;rr<4;++rr){
        int n  = wv*16 + quad*4 + rr;
        int kc = j*16 + l16;
        sKV[n*68 + kc] += accU[j][rr];
      }
    __syncthreads();   // (E) state update visible for next chunk
  }
}

// ---------- residual add + LayerNorm (row = 512) ----------
__global__ __launch_bounds__(256) void add_ln_kernel(
    const float* x, const float* y, const float* g, const float* bta,
    float* outf, unsigned short* outb, void* outd, const int* flag, int rows)
{
  int row = blockIdx.x*4 + (threadIdx.x >> 6);
  int lane = threadIdx.x & 63;
  if (row >= rows) return;
  const float* xr = x + (size_t)row*512;
  float a[8];
  *(float4*)&a[0] = *(const float4*)(xr + lane*4);
  *(float4*)&a[4] = *(const float4*)(xr + 256 + lane*4);
  if (y){
    const float* yr = y + (size_t)row*512;
    float ybuf[8];
    *(float4*)&ybuf[0] = *(const float4*)(yr + lane*4);
    *(float4*)&ybuf[4] = *(const float4*)(yr + 256 + lane*4);
    #pragma unroll
    for (int e=0;e<8;++e) a[e] += ybuf[e];
  }
  float s = 0.f, qq = 0.f;
  #pragma unroll
  for (int e=0;e<8;++e){ s += a[e]; qq += a[e]*a[e]; }
  #pragma unroll
  for (int off=32; off>0; off>>=1){
    s  += __shfl_xor(s,  off, 64);
    qq += __shfl_xor(qq, off, 64);
  }
  float mean = s * (1.f/512.f);
  float var  = qq * (1.f/512.f) - mean*mean;
  float rstd = rsqrtf(var + 1e-5f);
  float gg[8], bb[8];
  *(float4*)&gg[0] = *(const float4*)(g + lane*4);
  *(float4*)&gg[4] = *(const float4*)(g + 256 + lane*4);
  *(float4*)&bb[0] = *(const float4*)(bta + lane*4);
  *(float4*)&bb[4] = *(const float4*)(bta + 256 + lane*4);
  #pragma unroll
  for (int e=0;e<8;++e) a[e] = (a[e]-mean)*rstd*gg[e] + bb[e];
  if (outf){
    float* orow = outf + (size_t)row*512;
    *(float4*)(orow + lane*4)       = *(float4*)&a[0];
    *(float4*)(orow + 256 + lane*4) = *(float4*)&a[4];
  }
  if (outb){
    unsigned short* orow = outb + (size_t)row*512;
    #pragma unroll
    for (int e=0;e<4;++e){ orow[lane*4+e] = f2b(a[e]); orow[256+lane*4+e] = f2b(a[4+e]); }
  }
  if (outd){
    if (*flag){
      unsigned short* od = (unsigned short*)outd + (size_t)row*512;
      #pragma unroll
      for (int e=0;e<4;++e){ od[lane*4+e] = f2b(a[e]); od[256+lane*4+e] = f2b(a[4+e]); }
    } else {
      float* od = (float*)outd + (size_t)row*512;
      *(float4*)(od + lane*4)       = *(float4*)&a[0];
      *(float4*)(od + 256 + lane*4) = *(float4*)&a[4];
    }
  }
}

// ---------- host ----------
extern "C" void kernel_launch(void* const* d_in, const int* in_sizes, int n_in,
                              void* d_out, int out_size, void* d_ws, size_t ws_size,
                              hipStream_t stream)
{
  (void)in_sizes; (void)n_in; (void)out_size; (void)ws_size;
  const void* src = d_in[0];
  const void* Wq = d_in[1];  const void* bq = d_in[2];
  const void* Wk = d_in[3];  const void* bk = d_in[4];
  const void* Wv = d_in[5];  const void* bv = d_in[6];
  const void* Wo = d_in[7];  const void* bo = d_in[8];
  const void* W1 = d_in[9];  const void* b1 = d_in[10];
  const void* W2 = d_in[11]; const void* b2 = d_in[12];
  const void* g1 = d_in[13]; const void* be1 = d_in[14];
  const void* g2 = d_in[15]; const void* be2 = d_in[16];
  const void* gf = d_in[17]; const void* bef = d_in[18];

  char* W = (char*)d_ws;
  int* flag              = (int*)W;
  float* smalls          = (float*)(W + 256);
  unsigned short* wt     = (unsigned short*)(W + 65536);
  float* x_f             = (float*)(W + 12648448);
  unsigned short* x_b    = (unsigned short*)(W + 16842752);
  unsigned short* q_b    = (unsigned short*)(W + 18939904);
  unsigned short* k_b    = (unsigned short*)(W + 21037056);
  unsigned short* v_b    = (unsigned short*)(W + 23134208);
  unsigned short* att_b  = (unsigned short*)(W + 25231360);
  float* tmp_f           = (float*)(W + 27328512);
  unsigned short* h1_b   = (unsigned short*)(W + 31522816);

  detect_kernel<<<1, 256, 0, stream>>>(src, flag);

  // weights: per layer Wq,Wk,Wv,Wo (512x512), W1 (512x2048), W2 (2048x512)
  WParams wp;
  {
    const void* wsrc[6] = {Wq, Wk, Wv, Wo, W1, W2};
    int wK[6] = {512,512,512,512,512,2048};
    int wN[6] = {512,512,512,512,2048,512};
    long wsz[6] = {262144,262144,262144,262144,1048576,1048576};
    int tstart = 0; size_t dsto = 0;
    for (int l=0;l<2;++l)
      for (int ti=0;ti<6;++ti){
        int idx = l*6+ti;
        wp.d[idx].src = wsrc[ti];
        wp.d[idx].src_off = (long)l * wsz[ti];
        wp.d[idx].dst = wt + dsto;
        wp.d[idx].K = wK[ti]; wp.d[idx].N = wN[ti];
        wp.d[idx].tstart = tstart;
        tstart += (wK[ti]/32)*(wN[ti]/32);
        dsto += (size_t)wsz[ti];
      }
    wp.flag = flag;
    ingest_weights<<<dim3(6144), 256, 0, stream>>>(wp);
  }

  SParams sp;
  {
    const void* ssrc[12] = {bq,bk,bv,bo,b1,b2,g1,be1,g2,be2,gf,bef};
    int ssz[12] = {1024,1024,1024,1024,4096,1024,1024,1024,1024,1024,512,512};
    int st = 0;
    for (int i=0;i<12;++i){ sp.d[i].src = ssrc[i]; sp.d[i].start = st; st += ssz[i]; }
    sp.dst = smalls; sp.flag = flag; sp.total = st;   // 14336
    ingest_smalls<<<dim3(56), 256, 0, stream>>>(sp);
  }

  ingest_src<<<dim3(4096), 256, 0, stream>>>(src, flag, x_f, x_b, 1048576);

  for (int l = 0; l < 2; ++l){
    unsigned short* WqT = wt + (size_t)l*3145728;
    unsigned short* WkT = WqT + 262144;
    unsigned short* WvT = WqT + 524288;
    unsigned short* WoT = WqT + 786432;
    unsigned short* W1T = WqT + 1048576;
    unsigned short* W2T = WqT + 2097152;
    float* p_bq  = smalls + 0     + l*512;
    float* p_bk  = smalls + 1024  + l*512;
    float* p_bv  = smalls + 2048  + l*512;
    float* p_bo  = smalls + 3072  + l*512;
    float* p_b1  = smalls + 4096  + l*2048;
    float* p_b2  = smalls + 8192  + l*512;
    float* p_g1  = smalls + 9216  + l*512;
    float* p_be1 = smalls + 10240 + l*512;
    float* p_g2  = smalls + 11264 + l*512;
    float* p_be2 = smalls + 12288 + l*512;

    GemmArgs qkv;
    qkv.A = x_b;
    qkv.Bt[0]=WqT; qkv.Bt[1]=WkT; qkv.Bt[2]=WvT;
    qkv.bias[0]=p_bq; qkv.bias[1]=p_bk; qkv.bias[2]=p_bv;
    qkv.Cf[0]=nullptr; qkv.Cf[1]=nullptr; qkv.Cf[2]=nullptr;
    qkv.Cb[0]=q_b; qkv.Cb[1]=k_b; qkv.Cb[2]=v_b;
    qkv.M=2048; qkv.N=512; qkv.K=512; qkv.relu=0;
    gemm_bt<<<dim3(4,16,3), 256, 0, stream>>>(qkv);

    attn_kernel<<<dim3(16), 256, 0, stream>>>(q_b, k_b, v_b, att_b);

    GemmArgs go;
    go.A = att_b;
    go.Bt[0]=WoT; go.Bt[1]=nullptr; go.Bt[2]=nullptr;
    go.bias[0]=p_bo; go.bias[1]=nullptr; go.bias[2]=nullptr;
    go.Cf[0]=tmp_f; go.Cf[1]=nullptr; go.Cf[2]=nullptr;
    go.Cb[0]=nullptr; go.Cb[1]=nullptr; go.Cb[2]=nullptr;
    go.M=2048; go.N=512; go.K=512; go.relu=0;
    gemm_bt<<<dim3(4,16,1), 256, 0, stream>>>(go);

    add_ln_kernel<<<dim3(512), 256, 0, stream>>>(x_f, tmp_f, p_g1, p_be1,
                                                 x_f, x_b, nullptr, flag, 2048);

    GemmArgs f1;
    f1.A = x_b;
    f1.Bt[0]=W1T; f1.Bt[1]=nullptr; f1.Bt[2]=nullptr;
    f1.bias[0]=p_b1; f1.bias[1]=nullptr; f1.bias[2]=nullptr;
    f1.Cf[0]=nullptr; f1.Cf[1]=nullptr; f1.Cf[2]=nullptr;
    f1.Cb[0]=h1_b; f1.Cb[1]=nullptr; f1.Cb[2]=nullptr;
    f1.M=2048; f1.N=2048; f1.K=512; f1.relu=1;
    gemm_bt<<<dim3(16,16,1), 256, 0, stream>>>(f1);

    GemmArgs f2;
    f2.A = h1_b;
    f2.Bt[0]=W2T; f2.Bt[1]=nullptr; f2.Bt[2]=nullptr;
    f2.bias[0]=p_b2; f2.bias[1]=nullptr; f2.bias[2]=nullptr;
    f2.Cf[0]=tmp_f; f2.Cf[1]=nullptr; f2.Cf[2]=nullptr;
    f2.Cb[0]=nullptr; f2.Cb[1]=nullptr; f2.Cb[2]=nullptr;
    f2.M=2048; f2.N=512; f2.K=2048; f2.relu=0;
    gemm_bt<<<dim3(4,16,1), 256, 0, stream>>>(f2);

    add_ln_kernel<<<dim3(512), 256, 0, stream>>>(x_f, tmp_f, p_g2, p_be2,
                                                 x_f, x_b, nullptr, flag, 2048);
  }

  // final LayerNorm -> d_out (dtype chosen by detected flag)
  add_ln_kernel<<<dim3(512), 256, 0, stream>>>(x_f, nullptr, smalls + 13312, smalls + 13824,
                                               nullptr, nullptr, d_out, flag, 2048);
}

// Round 2
// 314.073 us; speedup vs baseline: 1.4100x; 1.4100x over previous
//
#include <hip/hip_runtime.h>
#include <hip/hip_bf16.h>

#define DEV static __device__ __forceinline__

typedef __attribute__((ext_vector_type(8))) short short8;
typedef __attribute__((ext_vector_type(4))) float f32x4;

// ---------- helpers ----------
DEV unsigned short f2b(float f){
  unsigned int u = __float_as_uint(f);
  return (unsigned short)((u + 0x7FFFu + ((u >> 16) & 1u)) >> 16);  // RNE
}
DEV float b2f(unsigned short h){ return __uint_as_float(((unsigned int)h) << 16); }
DEV float load_in(const void* p, size_t i, int isbf){
  return isbf ? b2f(((const unsigned short*)p)[i]) : ((const float*)p)[i];
}
DEV void load_lds16(const unsigned short* g, unsigned short* l){
  __builtin_amdgcn_global_load_lds(
      (const __attribute__((address_space(1))) void*)g,
      (__attribute__((address_space(3))) void*)l, 16, 0, 0);
}

// ---------- dtype detection ----------
__global__ void detect_kernel(const void* src, int* flag){
  int tid = threadIdx.x;
  float v = b2f(((const unsigned short*)src)[2 * tid]);
  float av = fabsf(v);
  bool sane = ((av < 64.0f) && (av > 9.5e-7f)) || (v == 0.0f);
  unsigned long long m = __ballot(sane);
  __shared__ int cnt[4];
  if ((tid & 63) == 0) cnt[tid >> 6] = __popcll(m);
  __syncthreads();
  if (tid == 0) flag[0] = (cnt[0] + cnt[1] + cnt[2] + cnt[3] > 128) ? 1 : 0;
}

// ---------- weight ingest: fp32/bf16 [K][N] -> bf16 W^T [N][K] ----------
struct WDesc { const void* src; long src_off; unsigned short* dst; int K; int N; int tstart; };
struct WParams { WDesc d[12]; const int* flag; };

__global__ __launch_bounds__(256) void ingest_weights(WParams P){
  __shared__ float tile[32][33];
  int b = blockIdx.x;
  int t = 0;
  #pragma unroll
  for (int i = 1; i < 12; ++i) if (b >= P.d[i].tstart) t = i;
  WDesc d = P.d[t];
  int isbf = *P.flag;
  int r = b - d.tstart;
  int tiles_x = d.N >> 5;
  int tx = r % tiles_x, ty = r / tiles_x;
  int lx = threadIdx.x & 31, ly = threadIdx.x >> 5;   // 32 x 8
  #pragma unroll
  for (int i = 0; i < 4; ++i){
    int row = ty*32 + ly + i*8;
    int col = tx*32 + lx;
    tile[ly + i*8][lx] = load_in(d.src, (size_t)d.src_off + (size_t)row*d.N + col, isbf);
  }
  __syncthreads();
  #pragma unroll
  for (int i = 0; i < 4; ++i){
    int orow = tx*32 + ly + i*8;   // n
    int ocol = ty*32 + lx;         // k
    d.dst[(size_t)orow*d.K + ocol] = f2b(tile[lx][ly + i*8]);
  }
}

// ---------- small params ingest -> contiguous fp32 ----------
struct SDesc { const void* src; int start; };
struct SParams { SDesc d[12]; float* dst; const int* flag; int total; };

__global__ void ingest_smalls(SParams P){
  int i = blockIdx.x*256 + threadIdx.x;
  if (i >= P.total) return;
  int t = 0;
  #pragma unroll
  for (int j = 1; j < 12; ++j) if (i >= P.d[j].start) t = j;
  P.dst[i] = load_in(P.d[t].src, (size_t)(i - P.d[t].start), *P.flag);
}

__global__ void ingest_src(const void* src, const int* flag, float* xf,
                           unsigned short* xb, int n){
  int i = blockIdx.x*blockDim.x + threadIdx.x;
  if (i >= n) return;
  float v = load_in(src, (size_t)i, *flag);
  xf[i] = v; xb[i] = f2b(v);
}

// ---------- GEMM: C[M][N] = A[M][K] @ Bt[N][K]^T + bias (A,Bt bf16) ----------
// m97 pattern: global_load_lds width=16, unpadded [rows][32] LDS in lane order.
// BN=128: 4 waves 2x2, each 4x4 MFMA. BN=64: 4 waves stacked in M, each 2x4.
struct GemmArgs {
  const unsigned short* A;
  const unsigned short* Bt[3];
  const float* bias[3];
  float* Cf[3];
  unsigned short* Cb[3];
  int M, N, K, relu;
};

template<int BN>
__global__ __launch_bounds__(256) void gemm_bt(GemmArgs g){
  constexpr int NI = (BN == 128) ? 4 : 2;
  constexpr int NJ = 4;
  __shared__ __align__(16) unsigned short sA[128*32];
  __shared__ __align__(16) unsigned short sB[BN*32];
  int tid = threadIdx.x;
  int z = blockIdx.z;
  const unsigned short* A  = g.A;
  const unsigned short* Bt = g.Bt[z];
  int K = g.K, N = g.N;
  size_t bm = (size_t)blockIdx.y * 128, bn = (size_t)blockIdx.x * BN;
  int lane = tid & 63, wv = tid >> 6, quad = lane >> 4, l16 = lane & 15;
  int wm = (BN == 128) ? (wv >> 1) * 64 : wv * 32;
  int wn = (BN == 128) ? (wv & 1) * 64 : 0;
  f32x4 acc[NI][NJ];
  #pragma unroll
  for (int i=0;i<NI;++i)
    #pragma unroll
    for (int j=0;j<NJ;++j) acc[i][j] = (f32x4){0.f,0.f,0.f,0.f};
  const unsigned short* Ap = A  + (bm + (tid>>2))*K + (tid&3)*8;
  const unsigned short* Bp = Bt + (bn + (tid>>2))*K + (tid&3)*8;
  for (int ko = 0; ko < K; ko += 32){
    __syncthreads();   // previous iter's LDS reads done
    load_lds16(Ap + ko,                 &sA[tid*8]);
    load_lds16(Ap + (size_t)64*K + ko,  &sA[2048 + tid*8]);
    load_lds16(Bp + ko,                 &sB[tid*8]);
    if (BN == 128)
      load_lds16(Bp + (size_t)64*K + ko, &sB[2048 + tid*8]);
    __syncthreads();   // drain vmcnt, tiles visible
    short8 af[NI], bfv[NJ];
    #pragma unroll
    for (int i=0;i<NI;++i) af[i]  = *(const short8*)&sA[(wm + i*16 + l16)*32 + quad*8];
    #pragma unroll
    for (int j=0;j<NJ;++j) bfv[j] = *(const short8*)&sB[(wn + j*16 + l16)*32 + quad*8];
    #pragma unroll
    for (int i=0;i<NI;++i)
      #pragma unroll
      for (int j=0;j<NJ;++j)
        acc[i][j] = __builtin_amdgcn_mfma_f32_16x16x32_bf16(af[i], bfv[j], acc[i][j], 0,0,0);
  }
  const float* bias = g.bias[z];
  float* Cf = g.Cf[z];
  unsigned short* Cb = g.Cb[z];
  #pragma unroll
  for (int j=0;j<NJ;++j){
    int col = (int)bn + wn + j*16 + l16;
    float bv = bias[col];
    #pragma unroll
    for (int i=0;i<NI;++i){
      #pragma unroll
      for (int r=0;r<4;++r){
        int row = (int)bm + wm + i*16 + quad*4 + r;
        float v = acc[i][j][r] + bv;
        if (g.relu) v = fmaxf(v, 0.f);
        size_t idx = (size_t)row*N + col;
        if (Cf) Cf[idx] = v;
        if (Cb) Cb[idx] = f2b(v);
      }
    }
  }
}

// ---------- chunked causal linear attention, parallel over (bh, chunk) ----------
#define ATT_S 1024
#define ATT_D 512

// Pass A: states[bh][c] = V_c^T K_c   (64x64 fp32)
__global__ __launch_bounds__(256) void attn_state_kernel(
    const unsigned short* k, const unsigned short* v, float* states)
{
  __shared__ __align__(16) unsigned short sVt[64*72];
  __shared__ __align__(16) unsigned short sKt[64*72];
  int tid = threadIdx.x;
  int c = blockIdx.x, bh = blockIdx.y;
  int b = bh >> 3, h = bh & 7;
  const size_t base = ((size_t)b*ATT_S + (size_t)c*64)*ATT_D + h*64;
  int lane = tid & 63, wv = tid >> 6, quad = lane >> 4, l16 = lane & 15;

  int t = lane, vc = wv*8;
  const unsigned short* vp = v + base + (size_t)t*ATT_D;
  const unsigned short* kp = k + base + (size_t)t*ATT_D;
  float4 v0 = *(const float4*)(vp + vc);
  float4 v1 = *(const float4*)(vp + vc + 32);
  float4 k0 = *(const float4*)(kp + vc);
  float4 k1 = *(const float4*)(kp + vc + 32);
  {
    const unsigned short* pv0 = (const unsigned short*)&v0;
    const unsigned short* pv1 = (const unsigned short*)&v1;
    const unsigned short* pk0 = (const unsigned short*)&k0;
    const unsigned short* pk1 = (const unsigned short*)&k1;
    #pragma unroll
    for (int e = 0; e < 8; ++e){
      sVt[(vc+e)*72 + t]    = pv0[e];
      sVt[(vc+32+e)*72 + t] = pv1[e];
      sKt[(vc+e)*72 + t]    = pk0[e];
      sKt[(vc+32+e)*72 + t] = pk1[e];
    }
  }
  __syncthreads();

  f32x4 acc[4];
  #pragma unroll
  for (int j=0;j<4;++j) acc[j] = (f32x4){0.f,0.f,0.f,0.f};
  #pragma unroll
  for (int kk=0;kk<2;++kk){
    short8 a = *(const short8*)&sVt[(wv*16 + l16)*72 + kk*32 + quad*8];
    #pragma unroll
    for (int j=0;j<4;++j){
      short8 bb = *(const short8*)&sKt[(j*16 + l16)*72 + kk*32 + quad*8];
      acc[j] = __builtin_amdgcn_mfma_f32_16x16x32_bf16(a, bb, acc[j], 0,0,0);
    }
  }
  float* st = states + ((size_t)bh*16 + c)*4096;
  #pragma unroll
  for (int j=0;j<4;++j)
    #pragma unroll
    for (int rr=0;rr<4;++rr)
      st[(wv*16 + quad*4 + rr)*64 + j*16 + l16] = acc[j][rr];
}

// Pass B: att_c = Q_c @ (sum_{cc<c} states[cc]) + tril(Q_c K_c^T) @ V_c
__global__ __launch_bounds__(256) void attn_out_kernel(
    const unsigned short* q, const unsigned short* k, const unsigned short* v,
    const float* states, unsigned short* att)
{
  __shared__ __align__(16) unsigned short sQ [64*72];
  __shared__ __align__(16) unsigned short sK [64*72];   // K chunk, reused for S
  __shared__ __align__(16) unsigned short sVt[64*72];
  __shared__ __align__(16) float sKV[64*68];
  int tid = threadIdx.x;
  int c = blockIdx.x, bh = blockIdx.y;
  int b = bh >> 3, h = bh & 7;
  const size_t base = ((size_t)b*ATT_S + (size_t)c*64)*ATT_D + h*64;
  int lane = tid & 63, wv = tid >> 6, quad = lane >> 4, l16 = lane & 15;

  // exclusive prefix sum of chunk states (fp32)
  float4 racc[4];
  #pragma unroll
  for (int u=0;u<4;++u) racc[u] = (float4){0.f,0.f,0.f,0.f};
  const float* sbase = states + (size_t)bh*16*4096;
  for (int cc = 0; cc < c; ++cc){
    const float4* sp = (const float4*)(sbase + (size_t)cc*4096);
    #pragma unroll
    for (int u=0;u<4;++u){
      float4 t4 = sp[tid + u*256];
      racc[u].x += t4.x; racc[u].y += t4.y; racc[u].z += t4.z; racc[u].w += t4.w;
    }
  }
  #pragma unroll
  for (int u=0;u<4;++u){
    int e = (tid + u*256)*4;
    int row = e >> 6, col = e & 63;
    *(float4*)&sKV[row*68 + col] = racc[u];
  }

  // stage Q, K row-major; V transposed
  int r = tid >> 2, c8 = (tid & 3)*8;
  const unsigned short* qp = q + base + (size_t)r*ATT_D;
  const unsigned short* kp = k + base + (size_t)r*ATT_D;
  float4 q0 = *(const float4*)(qp + c8);
  float4 q1 = *(const float4*)(qp + c8 + 32);
  float4 k0 = *(const float4*)(kp + c8);
  float4 k1 = *(const float4*)(kp + c8 + 32);
  int t = lane, vc = wv*8;
  const unsigned short* vp = v + base + (size_t)t*ATT_D;
  float4 v0 = *(const float4*)(vp + vc);
  float4 v1 = *(const float4*)(vp + vc + 32);
  *(float4*)&sQ[r*72 + c8]      = q0;
  *(float4*)&sQ[r*72 + c8 + 32] = q1;
  *(float4*)&sK[r*72 + c8]      = k0;
  *(float4*)&sK[r*72 + c8 + 32] = k1;
  {
    const unsigned short* pv0 = (const unsigned short*)&v0;
    const unsigned short* pv1 = (const unsigned short*)&v1;
    #pragma unroll
    for (int e=0;e<8;++e){
      sVt[(vc+e)*72 + t]    = pv0[e];
      sVt[(vc+32+e)*72 + t] = pv1[e];
    }
  }
  __syncthreads();

  // S = Q K^T
  f32x4 accS[4];
  #pragma unroll
  for (int j=0;j<4;++j) accS[j] = (f32x4){0.f,0.f,0.f,0.f};
  #pragma unroll
  for (int kk=0;kk<2;++kk){
    short8 a = *(const short8*)&sQ[(wv*16 + l16)*72 + kk*32 + quad*8];
    #pragma unroll
    for (int j=0;j<4;++j){
      short8 bb = *(const short8*)&sK[(j*16 + l16)*72 + kk*32 + quad*8];
      accS[j] = __builtin_amdgcn_mfma_f32_16x16x32_bf16(a, bb, accS[j], 0,0,0);
    }
  }
  __syncthreads();   // all waves done reading sK

  // masked S -> sK (bf16)
  #pragma unroll
  for (int j=0;j<4;++j)
    #pragma unroll
    for (int rr=0;rr<4;++rr){
      int i  = wv*16 + quad*4 + rr;
      int cj = j*16 + l16;
      sK[i*72 + cj] = f2b((i >= cj) ? accS[j][rr] : 0.f);
    }

  // att = Q @ KV_prefix (state converted bf16 on the fly)
  f32x4 accO[4];
  #pragma unroll
  for (int j=0;j<4;++j) accO[j] = (f32x4){0.f,0.f,0.f,0.f};
  #pragma unroll
  for (int kk=0;kk<2;++kk){
    short8 a = *(const short8*)&sQ[(wv*16 + l16)*72 + kk*32 + quad*8];
    #pragma unroll
    for (int j=0;j<4;++j){
      const float* pf = &sKV[(j*16 + l16)*68 + kk*32 + quad*8];
      short8 bb;
      #pragma unroll
      for (int e=0;e<8;++e) ((unsigned short*)&bb)[e] = f2b(pf[e]);
      accO[j] = __builtin_amdgcn_mfma_f32_16x16x32_bf16(a, bb, accO[j], 0,0,0);
    }
  }
  __syncthreads();   // S visible to all waves

  // att += S @ V
  #pragma unroll
  for (int kk=0;kk<2;++kk){
    short8 a = *(const short8*)&sK[(wv*16 + l16)*72 + kk*32 + quad*8];
    #pragma unroll
    for (int j=0;j<4;++j){
      short8 bb = *(const short8*)&sVt[(j*16 + l16)*72 + kk*32 + quad*8];
      accO[j] = __builtin_amdgcn_mfma_f32_16x16x32_bf16(a, bb, accO[j], 0,0,0);
    }
  }
  #pragma unroll
  for (int j=0;j<4;++j)
    #pragma unroll
    for (int rr=0;rr<4;++rr){
      int i  = wv*16 + quad*4 + rr;
      int cj = j*16 + l16;
      att[base + (size_t)i*ATT_D + cj] = f2b(accO[j][rr]);
    }
}

// ---------- residual add + LayerNorm (row = 512) ----------
__global__ __launch_bounds__(256) void add_ln_kernel(
    const float* x, const float* y, const float* g, const float* bta,
    float* outf, unsigned short* outb, void* outd, const int* flag, int rows)
{
  int row = blockIdx.x*4 + (threadIdx.x >> 6);
  int lane = threadIdx.x & 63;
  if (row >= rows) return;
  const float* xr = x + (size_t)row*512;
  float a[8];
  *(float4*)&a[0] = *(const float4*)(xr + lane*4);
  *(float4*)&a[4] = *(const float4*)(xr + 256 + lane*4);
  if (y){
    const float* yr = y + (size_t)row*512;
    float ybuf[8];
    *(float4*)&ybuf[0] = *(const float4*)(yr + lane*4);
    *(float4*)&ybuf[4] = *(const float4*)(yr + 256 + lane*4);
    #pragma unroll
    for (int e=0;e<8;++e) a[e] += ybuf[e];
  }
  float s = 0.f, qq = 0.f;
  #pragma unroll
  for (int e=0;e<8;++e){ s += a[e]; qq += a[e]*a[e]; }
  #pragma unroll
  for (int off=32; off>0; off>>=1){
    s  += __shfl_xor(s,  off, 64);
    qq += __shfl_xor(qq, off, 64);
  }
  float mean = s * (1.f/512.f);
  float var  = qq * (1.f/512.f) - mean*mean;
  float rstd = rsqrtf(var + 1e-5f);
  float gg[8], bb[8];
  *(float4*)&gg[0] = *(const float4*)(g + lane*4);
  *(float4*)&gg[4] = *(const float4*)(g + 256 + lane*4);
  *(float4*)&bb[0] = *(const float4*)(bta + lane*4);
  *(float4*)&bb[4] = *(const float4*)(bta + 256 + lane*4);
  #pragma unroll
  for (int e=0;e<8;++e) a[e] = (a[e]-mean)*rstd*gg[e] + bb[e];
  if (outf){
    float* orow = outf + (size_t)row*512;
    *(float4*)(orow + lane*4)       = *(float4*)&a[0];
    *(float4*)(orow + 256 + lane*4) = *(float4*)&a[4];
  }
  if (outb){
    unsigned short* orow = outb + (size_t)row*512;
    #pragma unroll
    for (int e=0;e<4;++e){ orow[lane*4+e] = f2b(a[e]); orow[256+lane*4+e] = f2b(a[4+e]); }
  }
  if (outd){
    if (*flag){
      unsigned short* od = (unsigned short*)outd + (size_t)row*512;
      #pragma unroll
      for (int e=0;e<4;++e){ od[lane*4+e] = f2b(a[e]); od[256+lane*4+e] = f2b(a[4+e]); }
    } else {
      float* od = (float*)outd + (size_t)row*512;
      *(float4*)(od + lane*4)       = *(float4*)&a[0];
      *(float4*)(od + 256 + lane*4) = *(float4*)&a[4];
    }
  }
}

// ---------- host ----------
extern "C" void kernel_launch(void* const* d_in, const int* in_sizes, int n_in,
                              void* d_out, int out_size, void* d_ws, size_t ws_size,
                              hipStream_t stream)
{
  (void)in_sizes; (void)n_in; (void)out_size; (void)ws_size;
  const void* src = d_in[0];
  const void* Wq = d_in[1];  const void* bq = d_in[2];
  const void* Wk = d_in[3];  const void* bk = d_in[4];
  const void* Wv = d_in[5];  const void* bv = d_in[6];
  const void* Wo = d_in[7];  const void* bo = d_in[8];
  const void* W1 = d_in[9];  const void* b1 = d_in[10];
  const void* W2 = d_in[11]; const void* b2 = d_in[12];
  const void* g1 = d_in[13]; const void* be1 = d_in[14];
  const void* g2 = d_in[15]; const void* be2 = d_in[16];
  const void* gf = d_in[17]; const void* bef = d_in[18];

  char* W = (char*)d_ws;
  int* flag              = (int*)W;
  float* smalls          = (float*)(W + 256);
  unsigned short* wt     = (unsigned short*)(W + 65536);
  float* x_f             = (float*)(W + 12648448);
  unsigned short* x_b    = (unsigned short*)(W + 16842752);
  unsigned short* q_b    = (unsigned short*)(W + 18939904);
  unsigned short* k_b    = (unsigned short*)(W + 21037056);
  unsigned short* v_b    = (unsigned short*)(W + 23134208);
  unsigned short* att_b  = (unsigned short*)(W + 25231360);
  float* tmp_f           = (float*)(W + 27328512);
  unsigned short* h1_b   = (unsigned short*)(W + 31522816);
  float* states          = (float*)(W + 31522816);  // aliases h1_b (disjoint lifetime)

  detect_kernel<<<1, 256, 0, stream>>>(src, flag);

  WParams wp;
  {
    const void* wsrc[6] = {Wq, Wk, Wv, Wo, W1, W2};
    int wK[6] = {512,512,512,512,512,2048};
    int wN[6] = {512,512,512,512,2048,512};
    long wsz[6] = {262144,262144,262144,262144,1048576,1048576};
    int tstart = 0; size_t dsto = 0;
    for (int l=0;l<2;++l)
      for (int ti=0;ti<6;++ti){
        int idx = l*6+ti;
        wp.d[idx].src = wsrc[ti];
        wp.d[idx].src_off = (long)l * wsz[ti];
        wp.d[idx].dst = wt + dsto;
        wp.d[idx].K = wK[ti]; wp.d[idx].N = wN[ti];
        wp.d[idx].tstart = tstart;
        tstart += (wK[ti]/32)*(wN[ti]/32);
        dsto += (size_t)wsz[ti];
      }
    wp.flag = flag;
    ingest_weights<<<dim3(6144), 256, 0, stream>>>(wp);
  }

  SParams sp;
  {
    const void* ssrc[12] = {bq,bk,bv,bo,b1,b2,g1,be1,g2,be2,gf,bef};
    int ssz[12] = {1024,1024,1024,1024,4096,1024,1024,1024,1024,1024,512,512};
    int st = 0;
    for (int i=0;i<12;++i){ sp.d[i].src = ssrc[i]; sp.d[i].start = st; st += ssz[i]; }
    sp.dst = smalls; sp.flag = flag; sp.total = st;   // 14336
    ingest_smalls<<<dim3(56), 256, 0, stream>>>(sp);
  }

  ingest_src<<<dim3(4096), 256, 0, stream>>>(src, flag, x_f, x_b, 1048576);

  for (int l = 0; l < 2; ++l){
    unsigned short* WqT = wt + (size_t)l*3145728;
    unsigned short* WkT = WqT + 262144;
    unsigned short* WvT = WqT + 524288;
    unsigned short* WoT = WqT + 786432;
    unsigned short* W1T = WqT + 1048576;
    unsigned short* W2T = WqT + 2097152;
    float* p_bq  = smalls + 0     + l*512;
    float* p_bk  = smalls + 1024  + l*512;
    float* p_bv  = smalls + 2048  + l*512;
    float* p_bo  = smalls + 3072  + l*512;
    float* p_b1  = smalls + 4096  + l*2048;
    float* p_b2  = smalls + 8192  + l*512;
    float* p_g1  = smalls + 9216  + l*512;
    float* p_be1 = smalls + 10240 + l*512;
    float* p_g2  = smalls + 11264 + l*512;
    float* p_be2 = smalls + 12288 + l*512;

    GemmArgs qkv;
    qkv.A = x_b;
    qkv.Bt[0]=WqT; qkv.Bt[1]=WkT; qkv.Bt[2]=WvT;
    qkv.bias[0]=p_bq; qkv.bias[1]=p_bk; qkv.bias[2]=p_bv;
    qkv.Cf[0]=nullptr; qkv.Cf[1]=nullptr; qkv.Cf[2]=nullptr;
    qkv.Cb[0]=q_b; qkv.Cb[1]=k_b; qkv.Cb[2]=v_b;
    qkv.M=2048; qkv.N=512; qkv.K=512; qkv.relu=0;
    gemm_bt<64><<<dim3(8,16,3), 256, 0, stream>>>(qkv);

    attn_state_kernel<<<dim3(16,16), 256, 0, stream>>>(k_b, v_b, states);
    attn_out_kernel<<<dim3(16,16), 256, 0, stream>>>(q_b, k_b, v_b, states, att_b);

    GemmArgs go;
    go.A = att_b;
    go.Bt[0]=WoT; go.Bt[1]=nullptr; go.Bt[2]=nullptr;
    go.bias[0]=p_bo; go.bias[1]=nullptr; go.bias[2]=nullptr;
    go.Cf[0]=tmp_f; go.Cf[1]=nullptr; go.Cf[2]=nullptr;
    go.Cb[0]=nullptr; go.Cb[1]=nullptr; go.Cb[2]=nullptr;
    go.M=2048; go.N=512; go.K=512; go.relu=0;
    gemm_bt<64><<<dim3(8,16,1), 256, 0, stream>>>(go);

    add_ln_kernel<<<dim3(512), 256, 0, stream>>>(x_f, tmp_f, p_g1, p_be1,
                                                 x_f, x_b, nullptr, flag, 2048);

    GemmArgs f1;
    f1.A = x_b;
    f1.Bt[0]=W1T; f1.Bt[1]=nullptr; f1.Bt[2]=nullptr;
    f1.bias[0]=p_b1; f1.bias[1]=nullptr; f1.bias[2]=nullptr;
    f1.Cf[0]=nullptr; f1.Cf[1]=nullptr; f1.Cf[2]=nullptr;
    f1.Cb[0]=h1_b; f1.Cb[1]=nullptr; f1.Cb[2]=nullptr;
    f1.M=2048; f1.N=2048; f1.K=512; f1.relu=1;
    gemm_bt<128><<<dim3(16,16,1), 256, 0, stream>>>(f1);

    GemmArgs f2;
    f2.A = h1_b;
    f2.Bt[0]=W2T; f2.Bt[1]=nullptr; f2.Bt[2]=nullptr;
    f2.bias[0]=p_b2; f2.bias[1]=nullptr; f2.bias[2]=nullptr;
    f2.Cf[0]=tmp_f; f2.Cf[1]=nullptr; f2.Cf[2]=nullptr;
    f2.Cb[0]=nullptr; f2.Cb[1]=nullptr; f2.Cb[2]=nullptr;
    f2.M=2048; f2.N=512; f2.K=2048; f2.relu=0;
    gemm_bt<64><<<dim3(8,16,1), 256, 0, stream>>>(f2);

    add_ln_kernel<<<dim3(512), 256, 0, stream>>>(x_f, tmp_f, p_g2, p_be2,
                                                 x_f, x_b, nullptr, flag, 2048);
  }

  add_ln_kernel<<<dim3(512), 256, 0, stream>>>(x_f, nullptr, smalls + 13312, smalls + 13824,
                                               nullptr, nullptr, d_out, flag, 2048);
}

// Round 3
// 280.830 us; speedup vs baseline: 1.5769x; 1.1184x over previous
//
#include <hip/hip_runtime.h>
#include <hip/hip_bf16.h>

#define DEV static __device__ __forceinline__

typedef __attribute__((ext_vector_type(8))) short short8;
typedef __attribute__((ext_vector_type(4))) float f32x4;

// ---------- helpers ----------
DEV unsigned short f2b(float f){
  unsigned int u = __float_as_uint(f);
  return (unsigned short)((u + 0x7FFFu + ((u >> 16) & 1u)) >> 16);  // RNE
}
DEV float b2f(unsigned short h){ return __uint_as_float(((unsigned int)h) << 16); }
DEV float load_in(const void* p, size_t i, int isbf){
  return isbf ? b2f(((const unsigned short*)p)[i]) : ((const float*)p)[i];
}
DEV void load_lds16(const unsigned short* g, unsigned short* l){
  __builtin_amdgcn_global_load_lds(
      (const __attribute__((address_space(1))) void*)g,
      (__attribute__((address_space(3))) void*)l, 16, 0, 0);
}

// ---------- per-block dtype detection (no separate kernel, no serialization) ----
// fp32 storage: even ushort of each word is mantissa garbage -> rarely sane bf16.
DEV int detect_isbf_block(const void* src){
  __shared__ int cnt[4];
  int tid = threadIdx.x;
  float v = b2f(((const unsigned short*)src)[2 * tid]);
  float av = fabsf(v);
  bool sane = ((av < 64.0f) && (av > 9.5e-7f)) || (v == 0.0f);
  unsigned long long m = __ballot(sane);
  if ((tid & 63) == 0) cnt[tid >> 6] = __popcll(m);
  __syncthreads();
  int tot = cnt[0] + cnt[1] + cnt[2] + cnt[3];
  __syncthreads();
  return tot > 128;
}

// ---------- weight ingest: fp32/bf16 [K][N] -> bf16 W^T [N][K] ----------
struct WDesc { const void* src; long src_off; unsigned short* dst; int K; int N; int tstart; };
struct WParams { WDesc d[12]; const void* dsrc; };

__global__ __launch_bounds__(256) void ingest_weights(WParams P){
  __shared__ float tile[32][33];
  int isbf = detect_isbf_block(P.dsrc);
  int b = blockIdx.x;
  int t = 0;
  #pragma unroll
  for (int i = 1; i < 12; ++i) if (b >= P.d[i].tstart) t = i;
  WDesc d = P.d[t];
  int r = b - d.tstart;
  int tiles_x = d.N >> 5;
  int tx = r % tiles_x, ty = r / tiles_x;
  int lx = threadIdx.x & 31, ly = threadIdx.x >> 5;   // 32 x 8
  #pragma unroll
  for (int i = 0; i < 4; ++i){
    int row = ty*32 + ly + i*8;
    int col = tx*32 + lx;
    tile[ly + i*8][lx] = load_in(d.src, (size_t)d.src_off + (size_t)row*d.N + col, isbf);
  }
  __syncthreads();
  #pragma unroll
  for (int i = 0; i < 4; ++i){
    int orow = tx*32 + ly + i*8;   // n
    int ocol = ty*32 + lx;         // k
    d.dst[(size_t)orow*d.K + ocol] = f2b(tile[lx][ly + i*8]);
  }
}

// ---------- src + small params ingest (one kernel) ----------
struct SDesc { const void* src; int src_off; int dstart; };
struct SParams { SDesc d[22]; float* dst; int total; };

__global__ __launch_bounds__(256) void ingest_misc(SParams S, const void* src,
                                                   float* xf, unsigned short* xb){
  int isbf = detect_isbf_block(src);
  int b = blockIdx.x, tid = threadIdx.x;
  if (b < 4096){
    int i = b*256 + tid;
    float v = load_in(src, (size_t)i, isbf);
    xf[i] = v; xb[i] = f2b(v);
  } else {
    int i = (b - 4096)*256 + tid;
    if (i < S.total){
      int t = 0;
      #pragma unroll
      for (int j = 1; j < 22; ++j) if (i >= S.d[j].dstart) t = j;
      S.dst[i] = load_in(S.d[t].src, (size_t)S.d[t].src_off + (i - S.d[t].dstart), isbf);
    }
  }
}

// ---------- GEMM: C[M][N] = A[M][K] @ Bt[N][K]^T (+bias) (A,Bt bf16) ----------
// m97 pattern: global_load_lds width=16, unpadded [rows][32] LDS in lane order.
// blockIdx.z = K-split index (koff = z*K); Cf partials get z*cfz offset.
// Output col routing: idx = (col>>cshift)*cstride + row*ldc + (col&cmask)
// (qkv: cshift=9 routes cols [0,1536) to contiguous q/k/v buffers).
struct GemmArgs {
  const unsigned short* A;
  const unsigned short* Bt;
  const float* bias;      // nullable
  float* Cf;              // nullable (fp32 partial base)
  unsigned short* Cb;     // nullable (bf16 out)
  int K;                  // per-split K
  int lda, ldb, ldc;
  int cshift, cmask;
  size_t cstride;         // col-split stride (elements)
  size_t cfz;             // Cf z-stride (elements)
  int relu;
};

template<int BN>
__global__ __launch_bounds__(256) void gemm_bt(GemmArgs g){
  constexpr int NI = (BN == 128) ? 4 : 2;
  constexpr int NJ = 4;
  __shared__ __align__(16) unsigned short sA[128*32];
  __shared__ __align__(16) unsigned short sB[BN*32];
  int tid = threadIdx.x;
  int koff = blockIdx.z * g.K;
  int K = g.K, lda = g.lda, ldb = g.ldb;
  size_t bm = (size_t)blockIdx.y * 128, bn = (size_t)blockIdx.x * BN;
  int lane = tid & 63, wv = tid >> 6, quad = lane >> 4, l16 = lane & 15;
  int wm = (BN == 128) ? (wv >> 1) * 64 : wv * 32;
  int wn = (BN == 128) ? (wv & 1) * 64 : 0;
  f32x4 acc[NI][NJ];
  #pragma unroll
  for (int i=0;i<NI;++i)
    #pragma unroll
    for (int j=0;j<NJ;++j) acc[i][j] = (f32x4){0.f,0.f,0.f,0.f};
  const unsigned short* Ap = g.A  + (bm + (tid>>2))*lda + koff + (tid&3)*8;
  const unsigned short* Bp = g.Bt + (bn + (tid>>2))*ldb + koff + (tid&3)*8;
  for (int ko = 0; ko < K; ko += 32){
    __syncthreads();   // previous iter's LDS reads done
    load_lds16(Ap + ko,                  &sA[tid*8]);
    load_lds16(Ap + (size_t)64*lda + ko, &sA[2048 + tid*8]);
    load_lds16(Bp + ko,                  &sB[tid*8]);
    if (BN == 128)
      load_lds16(Bp + (size_t)64*ldb + ko, &sB[2048 + tid*8]);
    __syncthreads();   // drain vmcnt, tiles visible
    short8 af[NI], bfv[NJ];
    #pragma unroll
    for (int i=0;i<NI;++i) af[i]  = *(const short8*)&sA[(wm + i*16 + l16)*32 + quad*8];
    #pragma unroll
    for (int j=0;j<NJ;++j) bfv[j] = *(const short8*)&sB[(wn + j*16 + l16)*32 + quad*8];
    #pragma unroll
    for (int i=0;i<NI;++i)
      #pragma unroll
      for (int j=0;j<NJ;++j)
        acc[i][j] = __builtin_amdgcn_mfma_f32_16x16x32_bf16(af[i], bfv[j], acc[i][j], 0,0,0);
  }
  float* Cf = g.Cf ? g.Cf + (size_t)blockIdx.z * g.cfz : nullptr;
  unsigned short* Cb = g.Cb;
  #pragma unroll
  for (int j=0;j<NJ;++j){
    int col = (int)bn + wn + j*16 + l16;
    float bv = g.bias ? g.bias[col] : 0.f;
    size_t cbase = ((size_t)(col >> g.cshift))*g.cstride + (col & g.cmask);
    #pragma unroll
    for (int i=0;i<NI;++i){
      #pragma unroll
      for (int r=0;r<4;++r){
        int row = (int)bm + wm + i*16 + quad*4 + r;
        float v = acc[i][j][r] + bv;
        if (g.relu) v = fmaxf(v, 0.f);
        size_t idx = cbase + (size_t)row*g.ldc;
        if (Cf) Cf[idx] = v;
        if (Cb) Cb[idx] = f2b(v);
      }
    }
  }
}

// ---------- chunked causal linear attention, parallel over (bh, chunk) ----------
#define ATT_S 1024
#define ATT_D 512

// Pass A: states[bh][c] = V_c^T K_c   (64x64 fp32)
__global__ __launch_bounds__(256) void attn_state_kernel(
    const unsigned short* k, const unsigned short* v, float* states)
{
  __shared__ __align__(16) unsigned short sVt[64*72];
  __shared__ __align__(16) unsigned short sKt[64*72];
  int tid = threadIdx.x;
  int c = blockIdx.x, bh = blockIdx.y;
  int b = bh >> 3, h = bh & 7;
  const size_t base = ((size_t)b*ATT_S + (size_t)c*64)*ATT_D + h*64;
  int lane = tid & 63, wv = tid >> 6, quad = lane >> 4, l16 = lane & 15;

  int t = lane, vc = wv*8;
  const unsigned short* vp = v + base + (size_t)t*ATT_D;
  const unsigned short* kp = k + base + (size_t)t*ATT_D;
  float4 v0 = *(const float4*)(vp + vc);
  float4 v1 = *(const float4*)(vp + vc + 32);
  float4 k0 = *(const float4*)(kp + vc);
  float4 k1 = *(const float4*)(kp + vc + 32);
  {
    const unsigned short* pv0 = (const unsigned short*)&v0;
    const unsigned short* pv1 = (const unsigned short*)&v1;
    const unsigned short* pk0 = (const unsigned short*)&k0;
    const unsigned short* pk1 = (const unsigned short*)&k1;
    #pragma unroll
    for (int e = 0; e < 8; ++e){
      sVt[(vc+e)*72 + t]    = pv0[e];
      sVt[(vc+32+e)*72 + t] = pv1[e];
      sKt[(vc+e)*72 + t]    = pk0[e];
      sKt[(vc+32+e)*72 + t] = pk1[e];
    }
  }
  __syncthreads();

  f32x4 acc[4];
  #pragma unroll
  for (int j=0;j<4;++j) acc[j] = (f32x4){0.f,0.f,0.f,0.f};
  #pragma unroll
  for (int kk=0;kk<2;++kk){
    short8 a = *(const short8*)&sVt[(wv*16 + l16)*72 + kk*32 + quad*8];
    #pragma unroll
    for (int j=0;j<4;++j){
      short8 bb = *(const short8*)&sKt[(j*16 + l16)*72 + kk*32 + quad*8];
      acc[j] = __builtin_amdgcn_mfma_f32_16x16x32_bf16(a, bb, acc[j], 0,0,0);
    }
  }
  float* st = states + ((size_t)bh*16 + c)*4096;
  #pragma unroll
  for (int j=0;j<4;++j)
    #pragma unroll
    for (int rr=0;rr<4;++rr)
      st[(wv*16 + quad*4 + rr)*64 + j*16 + l16] = acc[j][rr];
}

// Pass B: att_c = Q_c @ (sum_{cc<c} states[cc]) + tril(Q_c K_c^T) @ V_c
__global__ __launch_bounds__(256) void attn_out_kernel(
    const unsigned short* q, const unsigned short* k, const unsigned short* v,
    const float* states, unsigned short* att)
{
  __shared__ __align__(16) unsigned short sQ [64*72];
  __shared__ __align__(16) unsigned short sK [64*72];   // K chunk, reused for S
  __shared__ __align__(16) unsigned short sVt[64*72];
  __shared__ __align__(16) float sKV[64*68];
  int tid = threadIdx.x;
  int c = blockIdx.x, bh = blockIdx.y;
  int b = bh >> 3, h = bh & 7;
  const size_t base = ((size_t)b*ATT_S + (size_t)c*64)*ATT_D + h*64;
  int lane = tid & 63, wv = tid >> 6, quad = lane >> 4, l16 = lane & 15;

  // exclusive prefix sum of chunk states (fp32)
  float4 racc[4];
  #pragma unroll
  for (int u=0;u<4;++u) racc[u] = (float4){0.f,0.f,0.f,0.f};
  const float* sbase = states + (size_t)bh*16*4096;
  for (int cc = 0; cc < c; ++cc){
    const float4* sp = (const float4*)(sbase + (size_t)cc*4096);
    #pragma unroll
    for (int u=0;u<4;++u){
      float4 t4 = sp[tid + u*256];
      racc[u].x += t4.x; racc[u].y += t4.y; racc[u].z += t4.z; racc[u].w += t4.w;
    }
  }
  #pragma unroll
  for (int u=0;u<4;++u){
    int e = (tid + u*256)*4;
    int row = e >> 6, col = e & 63;
    *(float4*)&sKV[row*68 + col] = racc[u];
  }

  // stage Q, K row-major; V transposed
  int r = tid >> 2, c8 = (tid & 3)*8;
  const unsigned short* qp = q + base + (size_t)r*ATT_D;
  const unsigned short* kp = k + base + (size_t)r*ATT_D;
  float4 q0 = *(const float4*)(qp + c8);
  float4 q1 = *(const float4*)(qp + c8 + 32);
  float4 k0 = *(const float4*)(kp + c8);
  float4 k1 = *(const float4*)(kp + c8 + 32);
  int t = lane, vc = wv*8;
  const unsigned short* vp = v + base + (size_t)t*ATT_D;
  float4 v0 = *(const float4*)(vp + vc);
  float4 v1 = *(const float4*)(vp + vc + 32);
  *(float4*)&sQ[r*72 + c8]      = q0;
  *(float4*)&sQ[r*72 + c8 + 32] = q1;
  *(float4*)&sK[r*72 + c8]      = k0;
  *(float4*)&sK[r*72 + c8 + 32] = k1;
  {
    const unsigned short* pv0 = (const unsigned short*)&v0;
    const unsigned short* pv1 = (const unsigned short*)&v1;
    #pragma unroll
    for (int e=0;e<8;++e){
      sVt[(vc+e)*72 + t]    = pv0[e];
      sVt[(vc+32+e)*72 + t] = pv1[e];
    }
  }
  __syncthreads();

  // S = Q K^T
  f32x4 accS[4];
  #pragma unroll
  for (int j=0;j<4;++j) accS[j] = (f32x4){0.f,0.f,0.f,0.f};
  #pragma unroll
  for (int kk=0;kk<2;++kk){
    short8 a = *(const short8*)&sQ[(wv*16 + l16)*72 + kk*32 + quad*8];
    #pragma unroll
    for (int j=0;j<4;++j){
      short8 bb = *(const short8*)&sK[(j*16 + l16)*72 + kk*32 + quad*8];
      accS[j] = __builtin_amdgcn_mfma_f32_16x16x32_bf16(a, bb, accS[j], 0,0,0);
    }
  }
  __syncthreads();   // all waves done reading sK

  // masked S -> sK (bf16)
  #pragma unroll
  for (int j=0;j<4;++j)
    #pragma unroll
    for (int rr=0;rr<4;++rr){
      int i  = wv*16 + quad*4 + rr;
      int cj = j*16 + l16;
      sK[i*72 + cj] = f2b((i >= cj) ? accS[j][rr] : 0.f);
    }

  // att = Q @ KV_prefix (state converted bf16 on the fly)
  f32x4 accO[4];
  #pragma unroll
  for (int j=0;j<4;++j) accO[j] = (f32x4){0.f,0.f,0.f,0.f};
  #pragma unroll
  for (int kk=0;kk<2;++kk){
    short8 a = *(const short8*)&sQ[(wv*16 + l16)*72 + kk*32 + quad*8];
    #pragma unroll
    for (int j=0;j<4;++j){
      const float* pf = &sKV[(j*16 + l16)*68 + kk*32 + quad*8];
      short8 bb;
      #pragma unroll
      for (int e=0;e<8;++e) ((unsigned short*)&bb)[e] = f2b(pf[e]);
      accO[j] = __builtin_amdgcn_mfma_f32_16x16x32_bf16(a, bb, accO[j], 0,0,0);
    }
  }
  __syncthreads();   // S visible to all waves

  // att += S @ V
  #pragma unroll
  for (int kk=0;kk<2;++kk){
    short8 a = *(const short8*)&sK[(wv*16 + l16)*72 + kk*32 + quad*8];
    #pragma unroll
    for (int j=0;j<4;++j){
      short8 bb = *(const short8*)&sVt[(j*16 + l16)*72 + kk*32 + quad*8];
      accO[j] = __builtin_amdgcn_mfma_f32_16x16x32_bf16(a, bb, accO[j], 0,0,0);
    }
  }
  #pragma unroll
  for (int j=0;j<4;++j)
    #pragma unroll
    for (int rr=0;rr<4;++rr){
      int i  = wv*16 + quad*4 + rr;
      int cj = j*16 + l16;
      att[base + (size_t)i*ATT_D + cj] = f2b(accO[j][rr]);
    }
}

// ---------- residual add (+ up to 4 fp32 partials + bias) + LayerNorm ----------
__global__ __launch_bounds__(256) void add_ln_kernel(
    const float* x, const float* p, int np, const float* bias,
    const float* g, const float* bta,
    float* outf, unsigned short* outb, void* outd, const void* dsrc, int rows)
{
  int isbf = 0;
  if (dsrc) isbf = detect_isbf_block(dsrc);
  int row = blockIdx.x*4 + (threadIdx.x >> 6);
  int lane = threadIdx.x & 63;
  if (row >= rows) return;
  const float* xr = x + (size_t)row*512;
  float a[8];
  *(float4*)&a[0] = *(const float4*)(xr + lane*4);
  *(float4*)&a[4] = *(const float4*)(xr + 256 + lane*4);
  for (int s = 0; s < np; ++s){
    const float* pr = p + (size_t)s*1048576 + (size_t)row*512;
    float yb[8];
    *(float4*)&yb[0] = *(const float4*)(pr + lane*4);
    *(float4*)&yb[4] = *(const float4*)(pr + 256 + lane*4);
    #pragma unroll
    for (int e=0;e<8;++e) a[e] += yb[e];
  }
  if (bias){
    float bb2[8];
    *(float4*)&bb2[0] = *(const float4*)(bias + lane*4);
    *(float4*)&bb2[4] = *(const float4*)(bias + 256 + lane*4);
    #pragma unroll
    for (int e=0;e<8;++e) a[e] += bb2[e];
  }
  float s = 0.f, qq = 0.f;
  #pragma unroll
  for (int e=0;e<8;++e){ s += a[e]; qq += a[e]*a[e]; }
  #pragma unroll
  for (int off=32; off>0; off>>=1){
    s  += __shfl_xor(s,  off, 64);
    qq += __shfl_xor(qq, off, 64);
  }
  float mean = s * (1.f/512.f);
  float var  = qq * (1.f/512.f) - mean*mean;
  float rstd = rsqrtf(var + 1e-5f);
  float gg[8], bb[8];
  *(float4*)&gg[0] = *(const float4*)(g + lane*4);
  *(float4*)&gg[4] = *(const float4*)(g + 256 + lane*4);
  *(float4*)&bb[0] = *(const float4*)(bta + lane*4);
  *(float4*)&bb[4] = *(const float4*)(bta + 256 + lane*4);
  #pragma unroll
  for (int e=0;e<8;++e) a[e] = (a[e]-mean)*rstd*gg[e] + bb[e];
  if (outf){
    float* orow = outf + (size_t)row*512;
    *(float4*)(orow + lane*4)       = *(float4*)&a[0];
    *(float4*)(orow + 256 + lane*4) = *(float4*)&a[4];
  }
  if (outb){
    unsigned short* orow = outb + (size_t)row*512;
    #pragma unroll
    for (int e=0;e<4;++e){ orow[lane*4+e] = f2b(a[e]); orow[256+lane*4+e] = f2b(a[4+e]); }
  }
  if (outd){
    if (isbf){
      unsigned short* od = (unsigned short*)outd + (size_t)row*512;
      #pragma unroll
      for (int e=0;e<4;++e){ od[lane*4+e] = f2b(a[e]); od[256+lane*4+e] = f2b(a[4+e]); }
    } else {
      float* od = (float*)outd + (size_t)row*512;
      *(float4*)(od + lane*4)       = *(float4*)&a[0];
      *(float4*)(od + 256 + lane*4) = *(float4*)&a[4];
    }
  }
}

// ---------- host ----------
extern "C" void kernel_launch(void* const* d_in, const int* in_sizes, int n_in,
                              void* d_out, int out_size, void* d_ws, size_t ws_size,
                              hipStream_t stream)
{
  (void)in_sizes; (void)n_in; (void)out_size; (void)ws_size;
  const void* src = d_in[0];
  const void* Wq = d_in[1];  const void* bq = d_in[2];
  const void* Wk = d_in[3];  const void* bk = d_in[4];
  const void* Wv = d_in[5];  const void* bv = d_in[6];
  const void* Wo = d_in[7];  const void* bo = d_in[8];
  const void* W1 = d_in[9];  const void* b1 = d_in[10];
  const void* W2 = d_in[11]; const void* b2 = d_in[12];
  const void* g1 = d_in[13]; const void* be1 = d_in[14];
  const void* g2 = d_in[15]; const void* be2 = d_in[16];
  const void* gf = d_in[17]; const void* bef = d_in[18];

  char* W = (char*)d_ws;
  float* smalls          = (float*)(W + 256);        // 14336 floats (permuted layout)
  unsigned short* wt     = (unsigned short*)(W + 65536);
  float* x_f             = (float*)(W + 12648448);
  unsigned short* x_b    = (unsigned short*)(W + 16842752);
  unsigned short* q_b    = (unsigned short*)(W + 18939904);  // q,k,v contiguous (2MB each)
  unsigned short* att_b  = (unsigned short*)(W + 25231360);
  float* pp              = (float*)(W + 27328512);   // 4 partial buffers, 4MB fp32 each
  unsigned short* h1_b   = (unsigned short*)(W + 44105728);  // 8MB
  float* states          = (float*)(W + 44105728);   // aliases h1_b (disjoint lifetime)
  unsigned short* k_b = q_b + 1048576;
  unsigned short* v_b = q_b + 2097152;

  // ---- weight ingest: per layer rows of wt: WqT|WkT|WvT (stacked=WqkvT)|WoT|W1T|W2T
  WParams wp;
  {
    const void* wsrc[6] = {Wq, Wk, Wv, Wo, W1, W2};
    int wK[6] = {512,512,512,512,512,2048};
    int wN[6] = {512,512,512,512,2048,512};
    long wsz[6] = {262144,262144,262144,262144,1048576,1048576};
    int tstart = 0; size_t dsto = 0;
    for (int l=0;l<2;++l)
      for (int ti=0;ti<6;++ti){
        int idx = l*6+ti;
        wp.d[idx].src = wsrc[ti];
        wp.d[idx].src_off = (long)l * wsz[ti];
        wp.d[idx].dst = wt + dsto;
        wp.d[idx].K = wK[ti]; wp.d[idx].N = wN[ti];
        wp.d[idx].tstart = tstart;
        tstart += (wK[ti]/32)*(wN[ti]/32);
        dsto += (size_t)wsz[ti];
      }
    wp.dsrc = src;
    ingest_weights<<<dim3(6144), 256, 0, stream>>>(wp);
  }

  // ---- smalls, permuted: per layer [bq|bk|bv|bo|b1|b2|g1|be1|g2|be2] then gf,bef
  SParams sp;
  {
    const void* ss[10] = {bq,bk,bv,bo,b1,b2,g1,be1,g2,be2};
    int slen[10] = {512,512,512,512,2048,512,512,512,512,512};
    int dcur = 0, di = 0;
    for (int l=0;l<2;++l)
      for (int ti=0;ti<10;++ti){
        sp.d[di].src = ss[ti];
        sp.d[di].src_off = l * slen[ti];
        sp.d[di].dstart = dcur;
        dcur += slen[ti]; ++di;
      }
    sp.d[20].src = gf;  sp.d[20].src_off = 0; sp.d[20].dstart = dcur; dcur += 512;
    sp.d[21].src = bef; sp.d[21].src_off = 0; sp.d[21].dstart = dcur; dcur += 512;
    sp.dst = smalls; sp.total = dcur;   // 14336
    ingest_misc<<<dim3(4152), 256, 0, stream>>>(sp, src, x_f, x_b);
  }

  for (int l = 0; l < 2; ++l){
    unsigned short* WqkvT = wt + (size_t)l*3145728;   // [1536][512]
    unsigned short* WoT   = WqkvT + 786432;           // [512][512]
    unsigned short* W1T   = WqkvT + 1048576;          // [2048][512]
    unsigned short* W2T   = WqkvT + 2097152;          // [512][2048]
    float* base  = smalls + l*6656;
    float* p_bqkv= base;           // 1536
    float* p_bo  = base + 1536;
    float* p_b1  = base + 2048;    // 2048
    float* p_b2  = base + 4096;
    float* p_g1  = base + 4608;
    float* p_be1 = base + 5120;
    float* p_g2  = base + 5632;
    float* p_be2 = base + 6144;

    // QKV: one GEMM, N=1536, output routed by col>>9 into contiguous q/k/v
    GemmArgs qkv = {};
    qkv.A = x_b; qkv.Bt = WqkvT; qkv.bias = p_bqkv;
    qkv.Cf = nullptr; qkv.Cb = q_b;
    qkv.K = 512; qkv.lda = 512; qkv.ldb = 512; qkv.ldc = 512;
    qkv.cshift = 9; qkv.cmask = 511; qkv.cstride = 1048576; qkv.cfz = 0; qkv.relu = 0;
    gemm_bt<64><<<dim3(24,16,1), 256, 0, stream>>>(qkv);

    attn_state_kernel<<<dim3(16,16), 256, 0, stream>>>(k_b, v_b, states);
    attn_out_kernel<<<dim3(16,16), 256, 0, stream>>>(q_b, k_b, v_b, states, att_b);

    // att @ Wo: K-split 2 -> fp32 partials (bias folded into LN)
    GemmArgs go = {};
    go.A = att_b; go.Bt = WoT; go.bias = nullptr;
    go.Cf = pp; go.Cb = nullptr;
    go.K = 256; go.lda = 512; go.ldb = 512; go.ldc = 512;
    go.cshift = 30; go.cmask = 0x3fffffff; go.cstride = 0; go.cfz = 1048576; go.relu = 0;
    gemm_bt<64><<<dim3(8,16,2), 256, 0, stream>>>(go);

    add_ln_kernel<<<dim3(512), 256, 0, stream>>>(x_f, pp, 2, p_bo, p_g1, p_be1,
                                                 x_f, x_b, nullptr, nullptr, 2048);

    // FFN up: N=2048, bias+relu fused, bf16 out
    GemmArgs f1 = {};
    f1.A = x_b; f1.Bt = W1T; f1.bias = p_b1;
    f1.Cf = nullptr; f1.Cb = h1_b;
    f1.K = 512; f1.lda = 512; f1.ldb = 512; f1.ldc = 2048;
    f1.cshift = 30; f1.cmask = 0x3fffffff; f1.cstride = 0; f1.cfz = 0; f1.relu = 1;
    gemm_bt<128><<<dim3(16,16,1), 256, 0, stream>>>(f1);

    // FFN down: K=2048 -> K-split 4 -> fp32 partials (bias folded into LN)
    GemmArgs f2 = {};
    f2.A = h1_b; f2.Bt = W2T; f2.bias = nullptr;
    f2.Cf = pp; f2.Cb = nullptr;
    f2.K = 512; f2.lda = 2048; f2.ldb = 2048; f2.ldc = 512;
    f2.cshift = 30; f2.cmask = 0x3fffffff; f2.cstride = 0; f2.cfz = 1048576; f2.relu = 0;
    gemm_bt<64><<<dim3(8,16,4), 256, 0, stream>>>(f2);

    add_ln_kernel<<<dim3(512), 256, 0, stream>>>(x_f, pp, 4, p_b2, p_g2, p_be2,
                                                 x_f, x_b, nullptr, nullptr, 2048);
  }

  add_ln_kernel<<<dim3(512), 256, 0, stream>>>(x_f, nullptr, 0, nullptr,
                                               smalls + 13312, smalls + 13824,
                                               nullptr, nullptr, d_out, src, 2048);
}